// Round 10
// baseline (139.804 us; speedup 1.0000x reference)
//
#include <hip/hip_runtime.h>
#include <hip/hip_bf16.h>

// OutlookAttention: B=8,H=56,W=56,C=192,heads=6,K=3,pad=1 — fp32 in/out
constexpr int NH = 56, NW = 56, NC = 192, AJ = 486;
constexpr int HWP = NH * NW;   // 3136
constexpr int NPIX = 8 * HWP;  // 25088
constexpr float SCALE = 0.17677669529663687f;  // 1/sqrt(32)
constexpr int TS = 12288;   // elems per 64-row tile: 6 strips * 64 rows * 32 k
constexpr int PD = 60;      // padded spatial dim (halo 2 each side)
constexpr int PROW = PD * NC;          // 11520
constexpr int PBATCH = PD * PD * NC;   // 691200

typedef __bf16 bf16x8 __attribute__((ext_vector_type(8)));
typedef float f32x4 __attribute__((ext_vector_type(4)));

__device__ __forceinline__ void gload16(const void* g, void* l) {
  __builtin_amdgcn_global_load_lds(
      (const __attribute__((address_space(1))) void*)g,
      (__attribute__((address_space(3))) void*)l, 16, 0, 0);
}

// tiled offset for (row, k) in a [tile64][strip6][row64][k32] operand
__device__ __forceinline__ size_t toff(int row, int k) {
  return (size_t)(row >> 6) * TS + (k >> 5) * 2048 + (row & 63) * 32 + (k & 31);
}

// ---------------------------------------------------------------------------
// P0: weights -> bf16 [n][k] tiled (Wat padded to 512 rows); x -> bf16 tiled;
//     zero the 2-wide border of v_pad (464 px/batch * 24 chunks * 8 = 89088).
// ---------------------------------------------------------------------------
__global__ __launch_bounds__(256) void k_prep4(const float* __restrict__ x,
                                               const float* __restrict__ Wv,
                                               const float* __restrict__ Wa,
                                               const float* __restrict__ Wp,
                                               __bf16* __restrict__ xb,
                                               __bf16* __restrict__ Wvt,
                                               __bf16* __restrict__ Wat,
                                               __bf16* __restrict__ Wpt,
                                               __bf16* __restrict__ v_pad) {
  const int bid = blockIdx.x;
  if (bid < 144) {
    const int i = bid * 256 + threadIdx.x;
    const int n = i / 192, k = i - n * 192;
    const size_t d = toff(n, k);
    Wvt[d] = (__bf16)Wv[k * 192 + n];
    Wpt[d] = (__bf16)Wp[k * 192 + n];
  } else if (bid < 528) {
    const int i = (bid - 144) * 256 + threadIdx.x;
    const int n = i / 192, k = i - n * 192;
    Wat[toff(n, k)] = (n < 486) ? (__bf16)Wa[k * 486 + n] : (__bf16)0.f;
  } else if (bid < 2880) {
    const size_t i = (size_t)(bid - 528) * 256 + threadIdx.x;
    const int pix = (int)(i / 24), c8 = (int)(i % 24) * 8;
    const float* src = x + (size_t)pix * 192 + c8;
    const float4 f0 = *(const float4*)src;
    const float4 f1 = *(const float4*)(src + 4);
    bf16x8 o8;
    o8[0] = (__bf16)f0.x; o8[1] = (__bf16)f0.y;
    o8[2] = (__bf16)f0.z; o8[3] = (__bf16)f0.w;
    o8[4] = (__bf16)f1.x; o8[5] = (__bf16)f1.y;
    o8[6] = (__bf16)f1.z; o8[7] = (__bf16)f1.w;
    *(bf16x8*)(xb + toff(pix, c8)) = o8;
  } else {  // border zeroing: 348 blocks
    const int cg = (bid - 2880) * 256 + threadIdx.x;  // [0, 89088)
    const int b = cg / 11136, rem = cg - b * 11136;
    const int n = rem / 24, ck = rem - n * 24;
    int r, c;
    if (n < 120)      { r = n / 60;             c = n - (n / 60) * 60; }
    else if (n < 240) { r = 58 + (n - 120) / 60; c = (n - 120) % 60; }
    else if (n < 352) { r = 2 + (n - 240) / 2;   c = (n - 240) & 1; }
    else              { r = 2 + (n - 352) / 2;   c = 58 + ((n - 352) & 1); }
    bf16x8 z;
    #pragma unroll
    for (int j = 0; j < 8; ++j) z[j] = (__bf16)0.f;
    *(bf16x8*)&v_pad[(size_t)b * PBATCH + r * PROW + c * 192 + ck * 8] = z;
  }
}

// ---------------------------------------------------------------------------
// Fused single-shot GEMM (64x64 tiles, whole K=192 staged once, one barrier).
// by<3 (V):  v_pad[b][y+2][x+2][ch] bf16 = xb @ Wvt^T
// by>=3 (L): lgT[j][pix] bf16 = (Wat @ xb^T + ba)*SCALE
// Identical staging + MFMA loop; epilogues via LDS bounce (128B stores).
// ---------------------------------------------------------------------------
__global__ __launch_bounds__(256) void k_mm2(const __bf16* __restrict__ xb,
                                             const __bf16* __restrict__ Wvt,
                                             const __bf16* __restrict__ Wat,
                                             const float* __restrict__ ba,
                                             __bf16* __restrict__ v_pad,
                                             __bf16* __restrict__ lgT) {
  __shared__ __bf16 As[64 * 192];
  __shared__ __bf16 Bs[64 * 192];
  const int t = threadIdx.x, lane = t & 63, w = t >> 6;
  const int wm = w >> 1, wn = w & 1;
  const bool vmode = (blockIdx.y < 3);
  const __bf16* Asrc = vmode ? xb + (size_t)blockIdx.x * TS
                             : Wat + (size_t)(blockIdx.y - 3) * TS;
  const __bf16* Bsrc = vmode ? Wvt + (size_t)blockIdx.y * TS
                             : xb + (size_t)blockIdx.x * TS;
  #pragma unroll
  for (int i = 0; i < 6; ++i) {
    const int cb = i * 256 + w * 64;
    gload16(Asrc + (size_t)(cb + lane) * 8, &As[cb * 8]);
    gload16(Bsrc + (size_t)(cb + lane) * 8, &Bs[cb * 8]);
  }
  f32x4 acc[2][2];
  #pragma unroll
  for (int mi = 0; mi < 2; ++mi)
    #pragma unroll
    for (int nj = 0; nj < 2; ++nj) acc[mi][nj] = (f32x4){0.f, 0.f, 0.f, 0.f};
  __syncthreads();
  #pragma unroll
  for (int ks = 0; ks < 6; ++ks) {
    bf16x8 af[2], bfr[2];
    #pragma unroll
    for (int mi = 0; mi < 2; ++mi)
      af[mi] = *(const bf16x8*)&As[(ks * 64 + wm * 32 + mi * 16 + (lane & 15)) * 32 + (lane >> 4) * 8];
    #pragma unroll
    for (int nj = 0; nj < 2; ++nj)
      bfr[nj] = *(const bf16x8*)&Bs[(ks * 64 + wn * 32 + nj * 16 + (lane & 15)) * 32 + (lane >> 4) * 8];
    #pragma unroll
    for (int mi = 0; mi < 2; ++mi)
      #pragma unroll
      for (int nj = 0; nj < 2; ++nj)
        acc[mi][nj] = __builtin_amdgcn_mfma_f32_16x16x32_bf16(af[mi], bfr[nj], acc[mi][nj], 0, 0, 0);
  }
  const int col_l = lane & 15, rq4 = (lane >> 4) * 4;
  __bf16* Cs = As;
  __syncthreads();
  #pragma unroll
  for (int nj = 0; nj < 2; ++nj) {
    const int ln = wn * 32 + nj * 16 + col_l;
    #pragma unroll
    for (int mi = 0; mi < 2; ++mi) {
      const int lmb = wm * 32 + mi * 16 + rq4;
      #pragma unroll
      for (int r = 0; r < 4; ++r) {
        float val = acc[mi][nj][r];
        if (!vmode) {
          const int j = (blockIdx.y - 3) * 64 + lmb + r;
          val = (val + ba[j < 486 ? j : 0]) * SCALE;
        }
        Cs[(lmb + r) * 72 + ln] = (__bf16)val;
      }
    }
  }
  __syncthreads();
  {
    const int lm = t >> 2, seg = t & 3;
    const bf16x8 c0 = *(const bf16x8*)&Cs[lm * 72 + seg * 16];
    const bf16x8 c1 = *(const bf16x8*)&Cs[lm * 72 + seg * 16 + 8];
    if (vmode) {
      const int pix = blockIdx.x * 64 + lm;
      const int b = pix / HWP, yx = pix - b * HWP;
      const int y = yx / NW, xq = yx - y * NW;
      const size_t dst = (size_t)b * PBATCH + (y + 2) * PROW + (xq + 2) * 192 +
                         blockIdx.y * 64 + seg * 16;
      *(bf16x8*)&v_pad[dst] = c0;
      *(bf16x8*)&v_pad[dst + 8] = c1;
    } else {
      const int j = (blockIdx.y - 3) * 64 + lm, pix = blockIdx.x * 64 + seg * 16;
      if (j < 486) {
        *(bf16x8*)&lgT[(size_t)j * NPIX + pix] = c0;
        *(bf16x8*)&lgT[(size_t)j * NPIX + pix + 8] = c1;
      }
    }
  }
}

// ---------------------------------------------------------------------------
// K-coef: fused softmax + delta-collapse. thread = dst pixel, blockIdx.y = head.
// ---------------------------------------------------------------------------
__global__ __launch_bounds__(256) void k_coef(const __bf16* __restrict__ lgT,
                                              __bf16* __restrict__ wcT) {
  const int p = blockIdx.x * 256 + threadIdx.x;
  const int head = blockIdx.y;
  const int b = p / HWP;
  const int yx = p - b * HWP;
  const int y = yx / NW, x = yx - y * NW;

  float wc[25];
  #pragma unroll
  for (int c = 0; c < 25; ++c) wc[c] = 0.f;

  #pragma unroll
  for (int ki = 0; ki < 3; ++ki) {
    const int h = y - ki + 1;
    if ((unsigned)h >= (unsigned)NH) continue;
    #pragma unroll
    for (int kj = 0; kj < 3; ++kj) {
      const int ww = x - kj + 1;
      if ((unsigned)ww >= (unsigned)NW) continue;
      const int src = b * HWP + h * NW + ww;
      const size_t base = (size_t)((head * 9 + ki * 3 + kj) * 9) * NPIX + src;
      float lt[9];
      #pragma unroll
      for (int l = 0; l < 9; ++l) lt[l] = (float)lgT[base + (size_t)l * NPIX];
      float m = lt[0];
      #pragma unroll
      for (int l = 1; l < 9; ++l) m = fmaxf(m, lt[l]);
      float s = 0.f;
      #pragma unroll
      for (int l = 0; l < 9; ++l) { lt[l] = __expf(lt[l] - m); s += lt[l]; }
      const float inv = 1.f / s;
      #pragma unroll
      for (int l = 0; l < 9; ++l) {
        const int li = l / 3, lj = l - li * 3;
        wc[(li - ki + 2) * 5 + (lj - kj + 2)] += lt[l] * inv;
      }
    }
  }
  #pragma unroll
  for (int c = 0; c < 25; ++c)
    wcT[(size_t)(head * 25 + c) * NPIX + p] = (__bf16)wc[c];
}

// ---------------------------------------------------------------------------
// K-att4: stencil gather with branch-free global_load_lds staging from the
// zero-padded v. 2x8-px tiles, 192 thr = channels. Writes o tiled.
// ---------------------------------------------------------------------------
__global__ __launch_bounds__(192) void k_att4(const __bf16* __restrict__ v_pad,
                                              const __bf16* __restrict__ wcT,
                                              __bf16* __restrict__ o) {
  const int bid = blockIdx.x;          // 7 * 28 * 8 = 1568
  const int cx = bid % 7;
  const int ry = (bid / 7) % 28;
  const int bb = bid / 196;
  const int y0 = ry * 2, x0 = cx * 8;
  const int p0 = bb * HWP + y0 * NW + x0;
  const int t = threadIdx.x, w = t >> 6;

  __shared__ __bf16 vs[72][192];   // rows y0..y0+5, cols x0..x0+11 (padded idx)
  __shared__ float wcs[16][6][28];

  const __bf16* vb = v_pad + (size_t)bb * PBATCH;
  #pragma unroll
  for (int i = 0; i < 9; ++i) {  // 1728 chunks, branch-free DMA
    const int u = i * 192 + t;
    const int cell = u / 24, ck = u - cell * 24;
    const int ri = cell / 12, ci = cell - ri * 12;
    gload16(vb + (size_t)(y0 + ri) * PROW + (x0 + ci) * 192 + ck * 8,
            &vs[0][0] + (i * 192 + w * 64) * 16 / 2);
  }
  if (t < 150) {
    const int head = t / 25, cc = t - head * 25;
    const bf16x8 w0 = *(const bf16x8*)&wcT[(size_t)t * NPIX + p0];
    const bf16x8 w1 = *(const bf16x8*)&wcT[(size_t)t * NPIX + p0 + NW];
    #pragma unroll
    for (int q = 0; q < 8; ++q) {
      wcs[q][head][cc] = (float)w0[q];
      wcs[8 + q][head][cc] = (float)w1[q];
    }
  }
  __syncthreads();

  const int ch = t, head = ch >> 5;
  float vr[6][12];
  #pragma unroll
  for (int ri = 0; ri < 6; ++ri)
    #pragma unroll
    for (int ci = 0; ci < 12; ++ci) vr[ri][ci] = (float)vs[ri * 12 + ci][ch];
  #pragma unroll
  for (int q = 0; q < 16; ++q) {
    const int qr = q >> 3, qc = q & 7;
    float coef[25];
    #pragma unroll
    for (int i = 0; i < 6; ++i)
      *(float4*)&coef[i * 4] = *(const float4*)&wcs[q][head][i * 4];
    coef[24] = wcs[q][head][24];
    float s = 0.f;
    #pragma unroll
    for (int di = 0; di < 5; ++di)
      #pragma unroll
      for (int dj = 0; dj < 5; ++dj) s += coef[di * 5 + dj] * vr[qr + di][qc + dj];
    const int px = p0 + qr * NW + qc;
    o[toff(px, ch)] = (__bf16)s;
  }
}

// ---------------------------------------------------------------------------
// Out GEMM: out[pix][ch] f32 = o @ Wpt^T + bp. Single-shot 64x64.
// ---------------------------------------------------------------------------
__global__ __launch_bounds__(256) void k_gemm_out(const __bf16* __restrict__ At,
                                                  const __bf16* __restrict__ Bt,
                                                  const float* __restrict__ bias,
                                                  float* __restrict__ C) {
  __shared__ __bf16 As[64 * 192];
  __shared__ __bf16 Bs[64 * 192];
  const int t = threadIdx.x, lane = t & 63, w = t >> 6;
  const int wm = w >> 1, wn = w & 1;
  const __bf16* Asrc = At + (size_t)blockIdx.x * TS;
  const __bf16* Bsrc = Bt + (size_t)blockIdx.y * TS;
  #pragma unroll
  for (int i = 0; i < 6; ++i) {
    const int cb = i * 256 + w * 64;
    gload16(Asrc + (size_t)(cb + lane) * 8, &As[cb * 8]);
    gload16(Bsrc + (size_t)(cb + lane) * 8, &Bs[cb * 8]);
  }
  f32x4 acc[2][2];
  #pragma unroll
  for (int mi = 0; mi < 2; ++mi)
    #pragma unroll
    for (int nj = 0; nj < 2; ++nj) acc[mi][nj] = (f32x4){0.f, 0.f, 0.f, 0.f};
  __syncthreads();
  #pragma unroll
  for (int ks = 0; ks < 6; ++ks) {
    bf16x8 af[2], bfr[2];
    #pragma unroll
    for (int mi = 0; mi < 2; ++mi)
      af[mi] = *(const bf16x8*)&As[(ks * 64 + wm * 32 + mi * 16 + (lane & 15)) * 32 + (lane >> 4) * 8];
    #pragma unroll
    for (int nj = 0; nj < 2; ++nj)
      bfr[nj] = *(const bf16x8*)&Bs[(ks * 64 + wn * 32 + nj * 16 + (lane & 15)) * 32 + (lane >> 4) * 8];
    #pragma unroll
    for (int mi = 0; mi < 2; ++mi)
      #pragma unroll
      for (int nj = 0; nj < 2; ++nj)
        acc[mi][nj] = __builtin_amdgcn_mfma_f32_16x16x32_bf16(af[mi], bfr[nj], acc[mi][nj], 0, 0, 0);
  }
  const int col_l = lane & 15, rq4 = (lane >> 4) * 4;
  #pragma unroll
  for (int nj = 0; nj < 2; ++nj) {
    const int ch = blockIdx.y * 64 + wn * 32 + nj * 16 + col_l;
    const float bv = bias[ch];
    #pragma unroll
    for (int mi = 0; mi < 2; ++mi) {
      const int pix = blockIdx.x * 64 + wm * 32 + mi * 16 + rq4;
      #pragma unroll
      for (int r = 0; r < 4; ++r)
        C[(size_t)(pix + r) * 192 + ch] = acc[mi][nj][r] + bv;
    }
  }
}

// ---------------------------------------------------------------------------
extern "C" void kernel_launch(void* const* d_in, const int* in_sizes, int n_in,
                              void* d_out, int out_size, void* d_ws,
                              size_t ws_size, hipStream_t stream) {
  (void)in_sizes; (void)n_in; (void)out_size; (void)ws_size;
  const float* x  = (const float*)d_in[0];
  const float* Wv = (const float*)d_in[1];
  const float* Wa = (const float*)d_in[2];
  const float* ba = (const float*)d_in[3];
  const float* Wp = (const float*)d_in[4];
  const float* bp = (const float*)d_in[5];

  char* ws = (char*)d_ws;  // ws_size = 256 MiB; we use ~53 MB
  __bf16* Wvt  = (__bf16*)(ws);                 //     73,728 B (tiled)
  __bf16* Wat  = (__bf16*)(ws + 73728);         //    196,608 B (512x192 tiled)
  __bf16* Wpt  = (__bf16*)(ws + 270336);        //     73,728 B (tiled)
  __bf16* xb   = (__bf16*)(ws + 344064);        //  9,633,792 B (tiled)
  __bf16* v_pad = (__bf16*)(ws + 9977856);      // 11,059,200 B (8x60x60x192)
  __bf16* lgT  = (__bf16*)(ws + 21037056);      // 24,385,536 B (486 x 25088)
  __bf16* wcT  = (__bf16*)(ws + 45422592);      //  7,526,400 B (150 x 25088)
  __bf16* o_ws = (__bf16*)(ws + 21037056);      // aliases lgT (dead after coef)

  k_prep4<<<3228, 256, 0, stream>>>(x, Wv, Wa, Wp, xb, Wvt, Wat, Wpt, v_pad);
  k_mm2<<<dim3(392, 11), 256, 0, stream>>>(xb, Wvt, Wat, ba, v_pad, lgT);
  k_coef<<<dim3(98, 6), 256, 0, stream>>>(lgT, wcT);
  k_att4<<<1568, 192, 0, stream>>>(v_pad, wcT, o_ws);
  k_gemm_out<<<dim3(392, 3), 256, 0, stream>>>(o_ws, Wpt, bp, (float*)d_out);
}

// Round 11
// 135.762 us; speedup vs baseline: 1.0298x; 1.0298x over previous
//
#include <hip/hip_runtime.h>
#include <hip/hip_bf16.h>

// OutlookAttention: B=8,H=56,W=56,C=192,heads=6,K=3,pad=1 — fp32 in/out
constexpr int NH = 56, NW = 56, NC = 192, AJ = 486;
constexpr int HWP = NH * NW;   // 3136
constexpr int NPIX = 8 * HWP;  // 25088
constexpr float SCALE = 0.17677669529663687f;  // 1/sqrt(32)
constexpr int TS = 12288;   // elems per 64-row tile: 6 strips * 64 rows * 32 k
constexpr int PD = 60;      // padded spatial dim (halo 2 each side)
constexpr int PROW = PD * NC;          // 11520
constexpr int PBATCH = PD * PD * NC;   // 691200

typedef __bf16 bf16x8 __attribute__((ext_vector_type(8)));
typedef float f32x4 __attribute__((ext_vector_type(4)));

__device__ __forceinline__ void gload16(const void* g, void* l) {
  __builtin_amdgcn_global_load_lds(
      (const __attribute__((address_space(1))) void*)g,
      (__attribute__((address_space(3))) void*)l, 16, 0, 0);
}

// tiled offset for (row, k) in a [tile64][strip6][row64][k32] operand
__device__ __forceinline__ size_t toff(int row, int k) {
  return (size_t)(row >> 6) * TS + (k >> 5) * 2048 + (row & 63) * 32 + (k & 31);
}

// ---------------------------------------------------------------------------
// P0: weights -> bf16 [n][k] tiled (Wat padded to 512 rows); x -> bf16 tiled;
//     zero the 2-wide border of v_pad.
// ---------------------------------------------------------------------------
__global__ __launch_bounds__(256) void k_prep4(const float* __restrict__ x,
                                               const float* __restrict__ Wv,
                                               const float* __restrict__ Wa,
                                               const float* __restrict__ Wp,
                                               __bf16* __restrict__ xb,
                                               __bf16* __restrict__ Wvt,
                                               __bf16* __restrict__ Wat,
                                               __bf16* __restrict__ Wpt,
                                               __bf16* __restrict__ v_pad) {
  const int bid = blockIdx.x;
  if (bid < 144) {
    const int i = bid * 256 + threadIdx.x;
    const int n = i / 192, k = i - n * 192;
    const size_t d = toff(n, k);
    Wvt[d] = (__bf16)Wv[k * 192 + n];
    Wpt[d] = (__bf16)Wp[k * 192 + n];
  } else if (bid < 528) {
    const int i = (bid - 144) * 256 + threadIdx.x;
    const int n = i / 192, k = i - n * 192;
    Wat[toff(n, k)] = (n < 486) ? (__bf16)Wa[k * 486 + n] : (__bf16)0.f;
  } else if (bid < 2880) {
    const size_t i = (size_t)(bid - 528) * 256 + threadIdx.x;
    const int pix = (int)(i / 24), c8 = (int)(i % 24) * 8;
    const float* src = x + (size_t)pix * 192 + c8;
    const float4 f0 = *(const float4*)src;
    const float4 f1 = *(const float4*)(src + 4);
    bf16x8 o8;
    o8[0] = (__bf16)f0.x; o8[1] = (__bf16)f0.y;
    o8[2] = (__bf16)f0.z; o8[3] = (__bf16)f0.w;
    o8[4] = (__bf16)f1.x; o8[5] = (__bf16)f1.y;
    o8[6] = (__bf16)f1.z; o8[7] = (__bf16)f1.w;
    *(bf16x8*)(xb + toff(pix, c8)) = o8;
  } else {  // border zeroing: 348 blocks, 89088 chunks
    const int cg = (bid - 2880) * 256 + threadIdx.x;
    const int b = cg / 11136, rem = cg - b * 11136;
    const int n = rem / 24, ck = rem - n * 24;
    int r, c;
    if (n < 120)      { r = n / 60;              c = n - (n / 60) * 60; }
    else if (n < 240) { r = 58 + (n - 120) / 60; c = (n - 120) % 60; }
    else if (n < 352) { r = 2 + (n - 240) / 2;   c = (n - 240) & 1; }
    else              { r = 2 + (n - 352) / 2;   c = 58 + ((n - 352) & 1); }
    bf16x8 z;
    #pragma unroll
    for (int j = 0; j < 8; ++j) z[j] = (__bf16)0.f;
    *(bf16x8*)&v_pad[(size_t)b * PBATCH + r * PROW + c * 192 + ck * 8] = z;
  }
}

// ---------------------------------------------------------------------------
// Single-shot GEMM: 64x64 tile, whole K=192 staged once, one main barrier.
// MODE 0: v_pad[b][y+2][x+2][ch] bf16 = xb @ Wvt^T   (grid 392 x 3)
// MODE 1: lgT[j][pix] bf16 = (Wat @ xb^T + ba)*SCALE (grid 392 x 8)
// LDS-bounce epilogue for 128B-coalesced bf16 stores.
// ---------------------------------------------------------------------------
template <int MODE>
__global__ __launch_bounds__(256) void k_gemm1(const __bf16* __restrict__ At,
                                               const __bf16* __restrict__ Bt,
                                               const float* __restrict__ bias,
                                               __bf16* __restrict__ C) {
  __shared__ __bf16 As[64 * 192];
  __shared__ __bf16 Bs[64 * 192];
  const int t = threadIdx.x, lane = t & 63, w = t >> 6;
  const int wm = w >> 1, wn = w & 1;
  const int a_tile = (MODE == 1) ? blockIdx.y : blockIdx.x;
  const int b_tile = (MODE == 1) ? blockIdx.x : blockIdx.y;
  const __bf16* Asrc = At + (size_t)a_tile * TS;
  const __bf16* Bsrc = Bt + (size_t)b_tile * TS;
  #pragma unroll
  for (int i = 0; i < 6; ++i) {
    const int cb = i * 256 + w * 64;
    gload16(Asrc + (size_t)(cb + lane) * 8, &As[cb * 8]);
    gload16(Bsrc + (size_t)(cb + lane) * 8, &Bs[cb * 8]);
  }
  f32x4 acc[2][2];
  #pragma unroll
  for (int mi = 0; mi < 2; ++mi)
    #pragma unroll
    for (int nj = 0; nj < 2; ++nj) acc[mi][nj] = (f32x4){0.f, 0.f, 0.f, 0.f};
  __syncthreads();
  #pragma unroll
  for (int ks = 0; ks < 6; ++ks) {
    bf16x8 af[2], bfr[2];
    #pragma unroll
    for (int mi = 0; mi < 2; ++mi)
      af[mi] = *(const bf16x8*)&As[(ks * 64 + wm * 32 + mi * 16 + (lane & 15)) * 32 + (lane >> 4) * 8];
    #pragma unroll
    for (int nj = 0; nj < 2; ++nj)
      bfr[nj] = *(const bf16x8*)&Bs[(ks * 64 + wn * 32 + nj * 16 + (lane & 15)) * 32 + (lane >> 4) * 8];
    #pragma unroll
    for (int mi = 0; mi < 2; ++mi)
      #pragma unroll
      for (int nj = 0; nj < 2; ++nj)
        acc[mi][nj] = __builtin_amdgcn_mfma_f32_16x16x32_bf16(af[mi], bfr[nj], acc[mi][nj], 0, 0, 0);
  }
  const int col_l = lane & 15, rq4 = (lane >> 4) * 4;
  __bf16* Cs = As;  // reuse (dead after MFMA loop)
  __syncthreads();
  #pragma unroll
  for (int nj = 0; nj < 2; ++nj) {
    const int ln = wn * 32 + nj * 16 + col_l;
    #pragma unroll
    for (int mi = 0; mi < 2; ++mi) {
      const int lmb = wm * 32 + mi * 16 + rq4;
      #pragma unroll
      for (int r = 0; r < 4; ++r) {
        float val = acc[mi][nj][r];
        if (MODE == 1) {
          const int j = blockIdx.y * 64 + lmb + r;
          val = (val + bias[j < 486 ? j : 0]) * SCALE;
        }
        Cs[(lmb + r) * 72 + ln] = (__bf16)val;
      }
    }
  }
  __syncthreads();
  {
    const int lm = t >> 2, seg = t & 3;  // 64 rows x 4 segments of 16
    const bf16x8 c0 = *(const bf16x8*)&Cs[lm * 72 + seg * 16];
    const bf16x8 c1 = *(const bf16x8*)&Cs[lm * 72 + seg * 16 + 8];
    if (MODE == 0) {
      const int pix = blockIdx.x * 64 + lm;
      const int b = pix / HWP, yx = pix - b * HWP;
      const int y = yx / NW, xq = yx - y * NW;
      const size_t dst = (size_t)b * PBATCH + (y + 2) * PROW + (xq + 2) * 192 +
                         blockIdx.y * 64 + seg * 16;
      *(bf16x8*)&C[dst] = c0;
      *(bf16x8*)&C[dst + 8] = c1;
    } else {
      const int j = blockIdx.y * 64 + lm, pix = blockIdx.x * 64 + seg * 16;
      if (j < 486) {
        *(bf16x8*)&C[(size_t)j * NPIX + pix] = c0;
        *(bf16x8*)&C[(size_t)j * NPIX + pix + 8] = c1;
      }
    }
  }
}

// ---------------------------------------------------------------------------
// K-coef: fused softmax + delta-collapse. thread = dst pixel, blockIdx.y = head.
// ---------------------------------------------------------------------------
__global__ __launch_bounds__(256) void k_coef(const __bf16* __restrict__ lgT,
                                              __bf16* __restrict__ wcT) {
  const int p = blockIdx.x * 256 + threadIdx.x;
  const int head = blockIdx.y;
  const int b = p / HWP;
  const int yx = p - b * HWP;
  const int y = yx / NW, x = yx - y * NW;

  float wc[25];
  #pragma unroll
  for (int c = 0; c < 25; ++c) wc[c] = 0.f;

  #pragma unroll
  for (int ki = 0; ki < 3; ++ki) {
    const int h = y - ki + 1;
    if ((unsigned)h >= (unsigned)NH) continue;
    #pragma unroll
    for (int kj = 0; kj < 3; ++kj) {
      const int ww = x - kj + 1;
      if ((unsigned)ww >= (unsigned)NW) continue;
      const int src = b * HWP + h * NW + ww;
      const size_t base = (size_t)((head * 9 + ki * 3 + kj) * 9) * NPIX + src;
      float lt[9];
      #pragma unroll
      for (int l = 0; l < 9; ++l) lt[l] = (float)lgT[base + (size_t)l * NPIX];
      float m = lt[0];
      #pragma unroll
      for (int l = 1; l < 9; ++l) m = fmaxf(m, lt[l]);
      float s = 0.f;
      #pragma unroll
      for (int l = 0; l < 9; ++l) { lt[l] = __expf(lt[l] - m); s += lt[l]; }
      const float inv = 1.f / s;
      #pragma unroll
      for (int l = 0; l < 9; ++l) {
        const int li = l / 3, lj = l - li * 3;
        wc[(li - ki + 2) * 5 + (lj - kj + 2)] += lt[l] * inv;
      }
    }
  }
  #pragma unroll
  for (int c = 0; c < 25; ++c)
    wcT[(size_t)(head * 25 + c) * NPIX + p] = (__bf16)wc[c];
}

// ---------------------------------------------------------------------------
// K-att4: stencil gather, branch-free global_load_lds staging from padded v.
// 2x8-px tiles, 192 thr = channels. Writes o in k-strip tiled layout.
// ---------------------------------------------------------------------------
__global__ __launch_bounds__(192) void k_att4(const __bf16* __restrict__ v_pad,
                                              const __bf16* __restrict__ wcT,
                                              __bf16* __restrict__ o) {
  const int bid = blockIdx.x;          // 7 * 28 * 8 = 1568
  const int cx = bid % 7;
  const int ry = (bid / 7) % 28;
  const int bb = bid / 196;
  const int y0 = ry * 2, x0 = cx * 8;
  const int p0 = bb * HWP + y0 * NW + x0;
  const int t = threadIdx.x, w = t >> 6;

  __shared__ __bf16 vs[72][192];   // rows y0..y0+5, cols x0..x0+11 (padded idx)
  __shared__ float wcs[16][6][28];

  const __bf16* vb = v_pad + (size_t)bb * PBATCH;
  #pragma unroll
  for (int i = 0; i < 9; ++i) {  // 1728 chunks, branch-free DMA
    const int u = i * 192 + t;
    const int cell = u / 24, ck = u - cell * 24;
    const int ri = cell / 12, ci = cell - ri * 12;
    gload16(vb + (size_t)(y0 + ri) * PROW + (x0 + ci) * 192 + ck * 8,
            &vs[0][0] + (size_t)(i * 192 + w * 64) * 8);
  }
  if (t < 150) {
    const int head = t / 25, cc = t - head * 25;
    const bf16x8 w0 = *(const bf16x8*)&wcT[(size_t)t * NPIX + p0];
    const bf16x8 w1 = *(const bf16x8*)&wcT[(size_t)t * NPIX + p0 + NW];
    #pragma unroll
    for (int q = 0; q < 8; ++q) {
      wcs[q][head][cc] = (float)w0[q];
      wcs[8 + q][head][cc] = (float)w1[q];
    }
  }
  __syncthreads();

  const int ch = t, head = ch >> 5;
  float vr[6][12];
  #pragma unroll
  for (int ri = 0; ri < 6; ++ri)
    #pragma unroll
    for (int ci = 0; ci < 12; ++ci) vr[ri][ci] = (float)vs[ri * 12 + ci][ch];
  #pragma unroll
  for (int q = 0; q < 16; ++q) {
    const int qr = q >> 3, qc = q & 7;
    float coef[25];
    #pragma unroll
    for (int i = 0; i < 6; ++i)
      *(float4*)&coef[i * 4] = *(const float4*)&wcs[q][head][i * 4];
    coef[24] = wcs[q][head][24];
    float s = 0.f;
    #pragma unroll
    for (int di = 0; di < 5; ++di)
      #pragma unroll
      for (int dj = 0; dj < 5; ++dj) s += coef[di * 5 + dj] * vr[qr + di][qc + dj];
    const int px = p0 + qr * NW + qc;
    o[toff(px, ch)] = (__bf16)s;
  }
}

// ---------------------------------------------------------------------------
// Out GEMM: out[pix][ch] f32 = o @ Wpt^T + bp. Single-shot 64x64.
// ---------------------------------------------------------------------------
__global__ __launch_bounds__(256) void k_gemm_out(const __bf16* __restrict__ At,
                                                  const __bf16* __restrict__ Bt,
                                                  const float* __restrict__ bias,
                                                  float* __restrict__ C) {
  __shared__ __bf16 As[64 * 192];
  __shared__ __bf16 Bs[64 * 192];
  const int t = threadIdx.x, lane = t & 63, w = t >> 6;
  const int wm = w >> 1, wn = w & 1;
  const __bf16* Asrc = At + (size_t)blockIdx.x * TS;
  const __bf16* Bsrc = Bt + (size_t)blockIdx.y * TS;
  #pragma unroll
  for (int i = 0; i < 6; ++i) {
    const int cb = i * 256 + w * 64;
    gload16(Asrc + (size_t)(cb + lane) * 8, &As[cb * 8]);
    gload16(Bsrc + (size_t)(cb + lane) * 8, &Bs[cb * 8]);
  }
  f32x4 acc[2][2];
  #pragma unroll
  for (int mi = 0; mi < 2; ++mi)
    #pragma unroll
    for (int nj = 0; nj < 2; ++nj) acc[mi][nj] = (f32x4){0.f, 0.f, 0.f, 0.f};
  __syncthreads();
  #pragma unroll
  for (int ks = 0; ks < 6; ++ks) {
    bf16x8 af[2], bfr[2];
    #pragma unroll
    for (int mi = 0; mi < 2; ++mi)
      af[mi] = *(const bf16x8*)&As[(ks * 64 + wm * 32 + mi * 16 + (lane & 15)) * 32 + (lane >> 4) * 8];
    #pragma unroll
    for (int nj = 0; nj < 2; ++nj)
      bfr[nj] = *(const bf16x8*)&Bs[(ks * 64 + wn * 32 + nj * 16 + (lane & 15)) * 32 + (lane >> 4) * 8];
    #pragma unroll
    for (int mi = 0; mi < 2; ++mi)
      #pragma unroll
      for (int nj = 0; nj < 2; ++nj)
        acc[mi][nj] = __builtin_amdgcn_mfma_f32_16x16x32_bf16(af[mi], bfr[nj], acc[mi][nj], 0, 0, 0);
  }
  const int col_l = lane & 15, rq4 = (lane >> 4) * 4;
  #pragma unroll
  for (int nj = 0; nj < 2; ++nj) {
    const int ch = blockIdx.y * 64 + wn * 32 + nj * 16 + col_l;
    const float bv = bias[ch];
    #pragma unroll
    for (int mi = 0; mi < 2; ++mi) {
      const int pix = blockIdx.x * 64 + wm * 32 + mi * 16 + rq4;
      #pragma unroll
      for (int r = 0; r < 4; ++r)
        C[(size_t)(pix + r) * 192 + ch] = acc[mi][nj][r] + bv;
    }
  }
}

// ---------------------------------------------------------------------------
extern "C" void kernel_launch(void* const* d_in, const int* in_sizes, int n_in,
                              void* d_out, int out_size, void* d_ws,
                              size_t ws_size, hipStream_t stream) {
  (void)in_sizes; (void)n_in; (void)out_size; (void)ws_size;
  const float* x  = (const float*)d_in[0];
  const float* Wv = (const float*)d_in[1];
  const float* Wa = (const float*)d_in[2];
  const float* ba = (const float*)d_in[3];
  const float* Wp = (const float*)d_in[4];
  const float* bp = (const float*)d_in[5];

  char* ws = (char*)d_ws;  // ws_size = 256 MiB; we use ~53 MB
  __bf16* Wvt  = (__bf16*)(ws);                 //     73,728 B (tiled)
  __bf16* Wat  = (__bf16*)(ws + 73728);         //    196,608 B (512x192 tiled)
  __bf16* Wpt  = (__bf16*)(ws + 270336);        //     73,728 B (tiled)
  __bf16* xb   = (__bf16*)(ws + 344064);        //  9,633,792 B (tiled)
  __bf16* v_pad = (__bf16*)(ws + 9977856);      // 11,059,200 B (8x60x60x192)
  __bf16* lgT  = (__bf16*)(ws + 21037056);      // 24,385,536 B (486 x 25088)
  __bf16* wcT  = (__bf16*)(ws + 45422592);      //  7,526,400 B (150 x 25088)
  __bf16* o_ws = (__bf16*)(ws + 21037056);      // aliases lgT (dead after coef)

  k_prep4<<<3228, 256, 0, stream>>>(x, Wv, Wa, Wp, xb, Wvt, Wat, Wpt, v_pad);
  k_gemm1<0><<<dim3(392, 3), 256, 0, stream>>>(xb, Wvt, nullptr, v_pad);
  k_gemm1<1><<<dim3(392, 8), 256, 0, stream>>>(Wat, xb, ba, lgT);
  k_coef<<<dim3(98, 6), 256, 0, stream>>>(lgT, wcT);
  k_att4<<<1568, 192, 0, stream>>>(v_pad, wcT, o_ws);
  k_gemm_out<<<dim3(392, 3), 256, 0, stream>>>(o_ws, Wpt, bp, (float*)d_out);
}